// Round 1
// baseline (176.698 us; speedup 1.0000x reference)
//
#include <hip/hip_runtime.h>
#include <math.h>

#define NDIMS 32
#define NANG 496          // 32*31/2
#define RT_STRIDE 36      // 144 B: 16B-aligned rows, only 4-way write conflict
#define COLS_PER_BLOCK 512

// Fused kernel: per-(m, column-chunk) block.
//  A: sin/cos table -> LDS
//  B: 496-step Givens chain fully in registers (lane j = column j), R^T -> LDS
//  C: out[i][col] = sum_k R[i][k] * x[k][col], 2 cols/thread, coalesced f32x2.
__global__ __launch_bounds__(256, 4)
void soot_kernel(const float* __restrict__ x,
                 const float* __restrict__ angles,
                 const float* __restrict__ mus,
                 float* __restrict__ out,
                 int S /* nSamples */)
{
    __shared__ float2 cs[NANG];
    __shared__ float  RT[NDIMS * RT_STRIDE];

    const int tid = threadIdx.x;
    const int m   = blockIdx.x;

    // ---- Phase A: cos/sin of the 496 angles ----
    for (int s0 = tid; s0 < NANG; s0 += 256) {
        float a = angles[(size_t)m * NANG + s0];
        float sv, cv;
        sincosf(a, &sv, &cv);
        cs[s0] = make_float2(cv, sv);
    }
    __syncthreads();

    // ---- Phase B: sequential Givens chain, lane j holds column j in regs ----
    if (tid < NDIMS) {
        const int j = tid;
        float r[NDIMS];
        #pragma unroll
        for (int i = 0; i < NDIMS; ++i) r[i] = (i == j) ? 1.0f : 0.0f;

        int sidx = 0;
        #pragma unroll
        for (int t = 0; t < NDIMS - 1; ++t) {
            #pragma unroll
            for (int b = t + 1; b < NDIMS; ++b) {
                const float2 v = cs[sidx]; ++sidx;     // constant-folded index
                const float c = v.x, sn = v.y;
                const float vt = r[t], vb = r[b];
                const float u  = sn * (vt + vb);       // match reference formulation
                r[t] = (c + sn) * vt - u;
                r[b] = (c - sn) * vb + u;
            }
        }
        // write R^T with mus folded in: RT[k][i] = mus[i] * mat[i][k], k = j
        #pragma unroll
        for (int i = 0; i < NDIMS; ++i)
            RT[j * RT_STRIDE + i] = r[i] * mus[(size_t)m * NDIMS + i];
    }
    __syncthreads();

    // ---- Phase C: matmul, 2 adjacent columns per thread ----
    const int col0 = blockIdx.y * COLS_PER_BLOCK + tid * 2;
    if (col0 + 1 >= S + 1) return;                     // S assumed even; no barriers below

    const size_t xbase = (size_t)m * NDIMS * S + col0;
    float2 acc[NDIMS];
    #pragma unroll
    for (int i = 0; i < NDIMS; ++i) acc[i] = make_float2(0.0f, 0.0f);

    #pragma unroll
    for (int k = 0; k < NDIMS; ++k) {
        const float2 xv = *reinterpret_cast<const float2*>(x + xbase + (size_t)k * S);
        #pragma unroll
        for (int i = 0; i < NDIMS; i += 4) {
            const float4 rv = *reinterpret_cast<const float4*>(&RT[k * RT_STRIDE + i]);
            acc[i + 0].x = fmaf(rv.x, xv.x, acc[i + 0].x);
            acc[i + 0].y = fmaf(rv.x, xv.y, acc[i + 0].y);
            acc[i + 1].x = fmaf(rv.y, xv.x, acc[i + 1].x);
            acc[i + 1].y = fmaf(rv.y, xv.y, acc[i + 1].y);
            acc[i + 2].x = fmaf(rv.z, xv.x, acc[i + 2].x);
            acc[i + 2].y = fmaf(rv.z, xv.y, acc[i + 2].y);
            acc[i + 3].x = fmaf(rv.w, xv.x, acc[i + 3].x);
            acc[i + 3].y = fmaf(rv.w, xv.y, acc[i + 3].y);
        }
    }

    float* op = out + (size_t)m * NDIMS * S + col0;
    #pragma unroll
    for (int i = 0; i < NDIMS; ++i)
        *reinterpret_cast<float2*>(op + (size_t)i * S) = acc[i];
}

extern "C" void kernel_launch(void* const* d_in, const int* in_sizes, int n_in,
                              void* d_out, int out_size, void* d_ws, size_t ws_size,
                              hipStream_t stream) {
    const float* x      = (const float*)d_in[0];
    const float* angles = (const float*)d_in[1];
    const float* mus    = (const float*)d_in[2];
    float* out          = (float*)d_out;

    const int M = in_sizes[1] / NANG;                  // 1024
    const int S = in_sizes[0] / (M * NDIMS);           // 2048

    dim3 grid(M, (S + COLS_PER_BLOCK - 1) / COLS_PER_BLOCK);
    soot_kernel<<<grid, 256, 0, stream>>>(x, angles, mus, out, S);
}

// Round 3
// 165.660 us; speedup vs baseline: 1.0666x; 1.0666x over previous
//
#include <hip/hip_runtime.h>
#include <math.h>

#define NDIMS 32
#define NANG 496          // 32*31/2
#define MPB 8             // matrices per gen_R block
#define COLS 1024         // columns per apply_R block (256 threads * 4)

typedef float f32x4 __attribute__((ext_vector_type(4)));

// ---------------- Kernel 1: build R^T (mus folded) into workspace ----------
// RT[m][k][i] = mus[m][i] * mat[m][i][k]   (so apply reads rows of RT per k)
__global__ __launch_bounds__(256)
void gen_R(const float* __restrict__ angles, const float* __restrict__ mus,
           float* __restrict__ RT)
{
    __shared__ float2 cs[MPB][NANG];      // 31744 B
    const int tid = threadIdx.x;
    const int m0  = blockIdx.x * MPB;

    for (int idx = tid; idx < MPB * NANG; idx += 256) {
        const int lm = idx / NANG, a = idx - lm * NANG;
        float sv, cv;
        sincosf(angles[(size_t)(m0 + lm) * NANG + a], &sv, &cv);
        cs[lm][a] = make_float2(cv, sv);
    }
    __syncthreads();

    const int lm = tid >> 5, j = tid & 31;   // lane j owns column j of mat[m]
    const int m  = m0 + lm;

    float r[NDIMS];
    #pragma unroll
    for (int i = 0; i < NDIMS; ++i) r[i] = (i == j) ? 1.0f : 0.0f;

    int sidx = 0;
    #pragma unroll
    for (int t = 0; t < NDIMS - 1; ++t) {
        #pragma unroll
        for (int b = t + 1; b < NDIMS; ++b) {
            const float2 v = cs[lm][sidx]; ++sidx;   // compile-time sidx
            const float c = v.x, sn = v.y;
            const float vt = r[t], vb = r[b];
            const float u  = sn * (vt + vb);
            r[t] = (c + sn) * vt - u;
            r[b] = (c - sn) * vb + u;
        }
    }

    float* dst = RT + (size_t)m * (NDIMS * NDIMS) + (size_t)j * NDIMS;
    const float* mu = mus + (size_t)m * NDIMS;
    #pragma unroll
    for (int i = 0; i < NDIMS; i += 4) {
        f32x4 v;
        v.x = r[i + 0] * mu[i + 0];
        v.y = r[i + 1] * mu[i + 1];
        v.z = r[i + 2] * mu[i + 2];
        v.w = r[i + 3] * mu[i + 3];
        *reinterpret_cast<f32x4*>(dst + i) = v;
    }
}

// ---------------- Kernel 2: out = R * x, pure streaming ---------------------
__global__ __launch_bounds__(256, 3)
void apply_R(const float* __restrict__ x, const float* __restrict__ RT,
             float* __restrict__ out, int S)
{
    __shared__ float rt[NDIMS * NDIMS];   // 4 KB
    const int tid = threadIdx.x;
    const int m   = blockIdx.x;

    {   // load this m's R^T (1024 floats) cooperatively
        const f32x4 v = *reinterpret_cast<const f32x4*>(
            RT + (size_t)m * (NDIMS * NDIMS) + tid * 4);
        *reinterpret_cast<f32x4*>(rt + tid * 4) = v;
    }
    __syncthreads();

    const int col0 = blockIdx.y * COLS + tid * 4;
    if (col0 >= S) return;

    const size_t base = (size_t)m * NDIMS * S + col0;

    if (col0 + 3 < S) {
        f32x4 acc[NDIMS];
        #pragma unroll
        for (int i = 0; i < NDIMS; ++i) acc[i] = (f32x4)0.0f;

        #pragma unroll
        for (int k = 0; k < NDIMS; ++k) {
            const f32x4 xv = __builtin_nontemporal_load(
                reinterpret_cast<const f32x4*>(x + base + (size_t)k * S));
            #pragma unroll
            for (int i = 0; i < NDIMS; i += 4) {
                const f32x4 rv = *reinterpret_cast<const f32x4*>(&rt[k * NDIMS + i]);
                acc[i + 0].x = fmaf(rv.x, xv.x, acc[i + 0].x);
                acc[i + 0].y = fmaf(rv.x, xv.y, acc[i + 0].y);
                acc[i + 0].z = fmaf(rv.x, xv.z, acc[i + 0].z);
                acc[i + 0].w = fmaf(rv.x, xv.w, acc[i + 0].w);
                acc[i + 1].x = fmaf(rv.y, xv.x, acc[i + 1].x);
                acc[i + 1].y = fmaf(rv.y, xv.y, acc[i + 1].y);
                acc[i + 1].z = fmaf(rv.y, xv.z, acc[i + 1].z);
                acc[i + 1].w = fmaf(rv.y, xv.w, acc[i + 1].w);
                acc[i + 2].x = fmaf(rv.z, xv.x, acc[i + 2].x);
                acc[i + 2].y = fmaf(rv.z, xv.y, acc[i + 2].y);
                acc[i + 2].z = fmaf(rv.z, xv.z, acc[i + 2].z);
                acc[i + 2].w = fmaf(rv.z, xv.w, acc[i + 2].w);
                acc[i + 3].x = fmaf(rv.w, xv.x, acc[i + 3].x);
                acc[i + 3].y = fmaf(rv.w, xv.y, acc[i + 3].y);
                acc[i + 3].z = fmaf(rv.w, xv.z, acc[i + 3].z);
                acc[i + 3].w = fmaf(rv.w, xv.w, acc[i + 3].w);
            }
        }

        float* op = out + base;
        #pragma unroll
        for (int i = 0; i < NDIMS; ++i)
            __builtin_nontemporal_store(acc[i],
                reinterpret_cast<f32x4*>(op + (size_t)i * S));
    } else {
        // scalar tail (S not multiple of 4) — not hit for S=2048
        for (int c = col0; c < S; ++c) {
            for (int i = 0; i < NDIMS; ++i) {
                float a = 0.f;
                for (int k = 0; k < NDIMS; ++k)
                    a = fmaf(rt[k * NDIMS + i], x[(size_t)m * NDIMS * S + (size_t)k * S + c], a);
                out[(size_t)m * NDIMS * S + (size_t)i * S + c] = a;
            }
        }
    }
}

// ---------------- Fallback: round-1 fused kernel (if ws too small) ----------
#define RT_STRIDE 36
__global__ __launch_bounds__(256, 4)
void soot_fused(const float* __restrict__ x, const float* __restrict__ angles,
                const float* __restrict__ mus, float* __restrict__ out, int S)
{
    __shared__ float2 cs[NANG];
    __shared__ float  RT[NDIMS * RT_STRIDE];
    const int tid = threadIdx.x;
    const int m   = blockIdx.x;

    for (int s0 = tid; s0 < NANG; s0 += 256) {
        float sv, cv;
        sincosf(angles[(size_t)m * NANG + s0], &sv, &cv);
        cs[s0] = make_float2(cv, sv);
    }
    __syncthreads();

    if (tid < NDIMS) {
        const int j = tid;
        float r[NDIMS];
        #pragma unroll
        for (int i = 0; i < NDIMS; ++i) r[i] = (i == j) ? 1.0f : 0.0f;
        int sidx = 0;
        #pragma unroll
        for (int t = 0; t < NDIMS - 1; ++t)
            #pragma unroll
            for (int b = t + 1; b < NDIMS; ++b) {
                const float2 v = cs[sidx]; ++sidx;
                const float c = v.x, sn = v.y;
                const float vt = r[t], vb = r[b];
                const float u  = sn * (vt + vb);
                r[t] = (c + sn) * vt - u;
                r[b] = (c - sn) * vb + u;
            }
        #pragma unroll
        for (int i = 0; i < NDIMS; ++i)
            RT[j * RT_STRIDE + i] = r[i] * mus[(size_t)m * NDIMS + i];
    }
    __syncthreads();

    const int col0 = blockIdx.y * 512 + tid * 2;
    if (col0 + 1 >= S + 1) return;
    const size_t xbase = (size_t)m * NDIMS * S + col0;
    float2 acc[NDIMS];
    #pragma unroll
    for (int i = 0; i < NDIMS; ++i) acc[i] = make_float2(0.f, 0.f);
    #pragma unroll
    for (int k = 0; k < NDIMS; ++k) {
        const float2 xv = *reinterpret_cast<const float2*>(x + xbase + (size_t)k * S);
        #pragma unroll
        for (int i = 0; i < NDIMS; i += 4) {
            const float4 rv = *reinterpret_cast<const float4*>(&RT[k * RT_STRIDE + i]);
            acc[i + 0].x = fmaf(rv.x, xv.x, acc[i + 0].x);
            acc[i + 0].y = fmaf(rv.x, xv.y, acc[i + 0].y);
            acc[i + 1].x = fmaf(rv.y, xv.x, acc[i + 1].x);
            acc[i + 1].y = fmaf(rv.y, xv.y, acc[i + 1].y);
            acc[i + 2].x = fmaf(rv.z, xv.x, acc[i + 2].x);
            acc[i + 2].y = fmaf(rv.z, xv.y, acc[i + 2].y);
            acc[i + 3].x = fmaf(rv.w, xv.x, acc[i + 3].x);
            acc[i + 3].y = fmaf(rv.w, xv.y, acc[i + 3].y);
        }
    }
    float* op = out + (size_t)m * NDIMS * S + col0;
    #pragma unroll
    for (int i = 0; i < NDIMS; ++i)
        *reinterpret_cast<float2*>(op + (size_t)i * S) = acc[i];
}

extern "C" void kernel_launch(void* const* d_in, const int* in_sizes, int n_in,
                              void* d_out, int out_size, void* d_ws, size_t ws_size,
                              hipStream_t stream) {
    const float* x      = (const float*)d_in[0];
    const float* angles = (const float*)d_in[1];
    const float* mus    = (const float*)d_in[2];
    float* out          = (float*)d_out;

    const int M = in_sizes[1] / NANG;              // 1024
    const int S = in_sizes[0] / (M * NDIMS);       // 2048

    const size_t rt_bytes = (size_t)M * NDIMS * NDIMS * sizeof(float);  // 4 MB
    if (ws_size >= rt_bytes && (M % MPB) == 0) {
        float* RT = (float*)d_ws;
        gen_R<<<dim3(M / MPB), 256, 0, stream>>>(angles, mus, RT);
        dim3 grid(M, (S + COLS - 1) / COLS);
        apply_R<<<grid, 256, 0, stream>>>(x, RT, out, S);
    } else {
        dim3 grid(M, (S + 511) / 512);
        soot_fused<<<grid, 256, 0, stream>>>(x, angles, mus, out, S);
    }
}

// Round 4
// 154.396 us; speedup vs baseline: 1.1444x; 1.0730x over previous
//
#include <hip/hip_runtime.h>
#include <math.h>

#define NDIMS 32
#define NANG 496          // 32*31/2
#define MPB 8             // matrices per gen_R block
#define CPB 256           // columns per apply block (1 col/thread)

typedef float f32x4 __attribute__((ext_vector_type(4)));

// ---------------- Kernel 1: build R^T (mus folded) into workspace ----------
// RTbuf[m][k][i] = mus[m][i] * R[i][k]
__global__ __launch_bounds__(256)
void gen_R(const float* __restrict__ angles, const float* __restrict__ mus,
           float* __restrict__ RT)
{
    __shared__ float2 cs[MPB][NANG];      // 31744 B
    const int tid = threadIdx.x;
    const int m0  = blockIdx.x * MPB;

    for (int idx = tid; idx < MPB * NANG; idx += 256) {
        const int lm = idx / NANG, a = idx - lm * NANG;
        float sv, cv;
        sincosf(angles[(size_t)(m0 + lm) * NANG + a], &sv, &cv);
        cs[lm][a] = make_float2(cv, sv);
    }
    __syncthreads();

    const int lm = tid >> 5, j = tid & 31;   // lane j owns column j of mat[m]
    const int m  = m0 + lm;

    float r[NDIMS];
    #pragma unroll
    for (int i = 0; i < NDIMS; ++i) r[i] = (i == j) ? 1.0f : 0.0f;

    int sidx = 0;
    #pragma unroll
    for (int t = 0; t < NDIMS - 1; ++t) {
        #pragma unroll
        for (int b = t + 1; b < NDIMS; ++b) {
            const float2 v = cs[lm][sidx]; ++sidx;   // compile-time sidx
            const float c = v.x, sn = v.y;
            const float vt = r[t], vb = r[b];
            const float u  = sn * (vt + vb);
            r[t] = (c + sn) * vt - u;
            r[b] = (c - sn) * vb + u;
        }
    }

    float* dst = RT + (size_t)m * (NDIMS * NDIMS) + (size_t)j * NDIMS;
    const float* mu = mus + (size_t)m * NDIMS;
    #pragma unroll
    for (int i = 0; i < NDIMS; i += 4) {
        f32x4 v;
        v.x = r[i + 0] * mu[i + 0];
        v.y = r[i + 1] * mu[i + 1];
        v.z = r[i + 2] * mu[i + 2];
        v.w = r[i + 3] * mu[i + 3];
        *reinterpret_cast<f32x4*>(dst + i) = v;
    }
}

// ---------------- Kernel 2: out = R * x, 1 column per thread ---------------
// Loads fully decoupled from FMAs: 32 independent dword loads into xk[],
// then FMA phase with rt broadcast rows from LDS. ~90 VGPR -> high occupancy
// and deep per-wave MLP (8 KB in flight per wave).
__global__ __launch_bounds__(256, 4)
void apply_R2(const float* __restrict__ x, const float* __restrict__ RT,
              float* __restrict__ out, int S)
{
    __shared__ float rt[NDIMS * NDIMS];   // 4 KB
    const int tid = threadIdx.x;
    const int m   = blockIdx.x;

    // stage this m's R^T (1024 floats) cooperatively, 1 f32x4 per thread
    *reinterpret_cast<f32x4*>(&rt[tid * 4]) =
        *reinterpret_cast<const f32x4*>(RT + (size_t)m * (NDIMS * NDIMS) + tid * 4);
    __syncthreads();

    const int col = blockIdx.y * CPB + tid;
    if (col >= S) return;

    const float* xp = x + (size_t)m * NDIMS * S + col;
    float*       op = out + (size_t)m * NDIMS * S + col;

    // phase 1: issue all 32 independent loads (deep MLP, no consumers yet)
    float xk[NDIMS];
    #pragma unroll
    for (int k = 0; k < NDIMS; ++k) xk[k] = xp[(size_t)k * S];

    // phase 2: FMAs; compiler inserts descending vmcnt waits per xk[k]
    float acc[NDIMS];
    #pragma unroll
    for (int i = 0; i < NDIMS; ++i) acc[i] = 0.0f;

    #pragma unroll
    for (int k = 0; k < NDIMS; ++k) {
        const float xv = xk[k];
        #pragma unroll
        for (int i = 0; i < NDIMS; i += 4) {
            const f32x4 rv = *reinterpret_cast<const f32x4*>(&rt[k * NDIMS + i]); // uniform -> broadcast
            acc[i + 0] = fmaf(rv.x, xv, acc[i + 0]);
            acc[i + 1] = fmaf(rv.y, xv, acc[i + 1]);
            acc[i + 2] = fmaf(rv.z, xv, acc[i + 2]);
            acc[i + 3] = fmaf(rv.w, xv, acc[i + 3]);
        }
    }

    // phase 3: 32 dword stores, 256 B contiguous per wave per row
    #pragma unroll
    for (int i = 0; i < NDIMS; ++i) op[(size_t)i * S] = acc[i];
}

// ---------------- Fallback: round-1 fused kernel (if ws too small) ----------
#define RT_STRIDE 36
__global__ __launch_bounds__(256, 4)
void soot_fused(const float* __restrict__ x, const float* __restrict__ angles,
                const float* __restrict__ mus, float* __restrict__ out, int S)
{
    __shared__ float2 cs[NANG];
    __shared__ float  RT[NDIMS * RT_STRIDE];
    const int tid = threadIdx.x;
    const int m   = blockIdx.x;

    for (int s0 = tid; s0 < NANG; s0 += 256) {
        float sv, cv;
        sincosf(angles[(size_t)m * NANG + s0], &sv, &cv);
        cs[s0] = make_float2(cv, sv);
    }
    __syncthreads();

    if (tid < NDIMS) {
        const int j = tid;
        float r[NDIMS];
        #pragma unroll
        for (int i = 0; i < NDIMS; ++i) r[i] = (i == j) ? 1.0f : 0.0f;
        int sidx = 0;
        #pragma unroll
        for (int t = 0; t < NDIMS - 1; ++t)
            #pragma unroll
            for (int b = t + 1; b < NDIMS; ++b) {
                const float2 v = cs[sidx]; ++sidx;
                const float c = v.x, sn = v.y;
                const float vt = r[t], vb = r[b];
                const float u  = sn * (vt + vb);
                r[t] = (c + sn) * vt - u;
                r[b] = (c - sn) * vb + u;
            }
        #pragma unroll
        for (int i = 0; i < NDIMS; ++i)
            RT[j * RT_STRIDE + i] = r[i] * mus[(size_t)m * NDIMS + i];
    }
    __syncthreads();

    const int col0 = blockIdx.y * 512 + tid * 2;
    if (col0 + 1 >= S + 1) return;
    const size_t xbase = (size_t)m * NDIMS * S + col0;
    float2 acc[NDIMS];
    #pragma unroll
    for (int i = 0; i < NDIMS; ++i) acc[i] = make_float2(0.f, 0.f);
    #pragma unroll
    for (int k = 0; k < NDIMS; ++k) {
        const float2 xv = *reinterpret_cast<const float2*>(x + xbase + (size_t)k * S);
        #pragma unroll
        for (int i = 0; i < NDIMS; i += 4) {
            const float4 rv = *reinterpret_cast<const float4*>(&RT[k * RT_STRIDE + i]);
            acc[i + 0].x = fmaf(rv.x, xv.x, acc[i + 0].x);
            acc[i + 0].y = fmaf(rv.x, xv.y, acc[i + 0].y);
            acc[i + 1].x = fmaf(rv.y, xv.x, acc[i + 1].x);
            acc[i + 1].y = fmaf(rv.y, xv.y, acc[i + 1].y);
            acc[i + 2].x = fmaf(rv.z, xv.x, acc[i + 2].x);
            acc[i + 2].y = fmaf(rv.z, xv.y, acc[i + 2].y);
            acc[i + 3].x = fmaf(rv.w, xv.x, acc[i + 3].x);
            acc[i + 3].y = fmaf(rv.w, xv.y, acc[i + 3].y);
        }
    }
    float* op = out + (size_t)m * NDIMS * S + col0;
    #pragma unroll
    for (int i = 0; i < NDIMS; ++i)
        *reinterpret_cast<float2*>(op + (size_t)i * S) = acc[i];
}

extern "C" void kernel_launch(void* const* d_in, const int* in_sizes, int n_in,
                              void* d_out, int out_size, void* d_ws, size_t ws_size,
                              hipStream_t stream) {
    const float* x      = (const float*)d_in[0];
    const float* angles = (const float*)d_in[1];
    const float* mus    = (const float*)d_in[2];
    float* out          = (float*)d_out;

    const int M = in_sizes[1] / NANG;              // 1024
    const int S = in_sizes[0] / (M * NDIMS);       // 2048

    const size_t rt_bytes = (size_t)M * NDIMS * NDIMS * sizeof(float);  // 4 MB
    if (ws_size >= rt_bytes && (M % MPB) == 0) {
        float* RT = (float*)d_ws;
        gen_R<<<dim3(M / MPB), 256, 0, stream>>>(angles, mus, RT);
        dim3 grid(M, (S + CPB - 1) / CPB);
        apply_R2<<<grid, 256, 0, stream>>>(x, RT, out, S);
    } else {
        dim3 grid(M, (S + 511) / 512);
        soot_fused<<<grid, 256, 0, stream>>>(x, angles, mus, out, S);
    }
}